// Round 16
// baseline (206.306 us; speedup 1.0000x reference)
//
#include <hip/hip_runtime.h>

#define TT 512

typedef _Float16 half8 __attribute__((ext_vector_type(8)));
typedef __attribute__((ext_vector_type(4))) float floatx4;

// raw workgroup barrier (no vmcnt/lgkmcnt drain); LDS FIFO is in-order per CU,
// validated R6-R12 (reads issued pre-barrier stay bit-exact vs post-barrier
// overwrites across 512 steps).
#define BAR() do { __asm__ volatile("" ::: "memory"); \
                   __builtin_amdgcn_s_barrier();      \
                   __asm__ volatile("" ::: "memory"); } while (0)

// 5-op tanh (R10 win, -32%): tanh(z) = fma(-2, rcp(exp2(z*2log2e)+1), 1).
__device__ __forceinline__ float fast_tanh(float z) {
#if __has_builtin(__builtin_amdgcn_exp2f)
    const float e = __builtin_amdgcn_exp2f(z * 2.8853900817779268f);
#else
    const float e = exp2f(z * 2.8853900817779268f);
#endif
#if __has_builtin(__builtin_amdgcn_rcpf)
    const float r = __builtin_amdgcn_rcpf(e + 1.f);
#else
    const float r = __frcp_rn(e + 1.f);
#endif
    return __builtin_fmaf(-2.f, r, 1.f);
}
__device__ __forceinline__ float f4e(const float4& v, int r) {
    return (r == 0) ? v.x : (r == 1) ? v.y : (r == 2) ? v.z : v.w;
}
__device__ __forceinline__ unsigned pk16(float a, float b) {
    const unsigned ua = __builtin_bit_cast(unsigned short, (_Float16)a);
    const unsigned ub = __builtin_bit_cast(unsigned short, (_Float16)b);
    return ua | (ub << 16);
}

// R16 = R14 champion (141.4 us: lag-2 pipeline, full MFMA C-in chaining,
// 5-op tanh, late h0-prefetch) + STATIC asymmetric wave priority.
// L0 waves (tempo-setters: their h0 feeds BOTH layers next interval) run at
// s_setprio(1) for the whole kernel; L1 waves stay at 0. At every barrier
// release the SIMD arbiter issues L0's exposed ds_read+chain first; L1 has
// two register-ready bp MFMAs to fill the gap. Distinct from R6's neutral
// symmetric-toggle (which differentiated nothing). One init instruction,
// zero steady-state cost, arithmetic bit-identical to R14 (absmax
// 4.882812e-4).
__global__ void __launch_bounds__(512, 1)
rnn2_prio2(const float* __restrict__ x,
           const float* __restrict__ W_ih0, const float* __restrict__ W_hh0,
           const float* __restrict__ b_ih0, const float* __restrict__ b_hh0,
           const float* __restrict__ W_ih1, const float* __restrict__ W_hh1,
           const float* __restrict__ b_ih1, const float* __restrict__ b_hh1,
           const float* __restrict__ W_fc, const float* __restrict__ b_fc,
           float* __restrict__ out)
{
    __shared__ short h0f[2][1024];  // [parity][chunk*512 + 128q + 8n + j], fp16
    __shared__ short h1f[2][1024];
    __shared__ float red[4][16];

    const int tid = threadIdx.x;
    const int lane = tid & 63;
    const int w = tid >> 6;          // 0..7
    const int wq = w & 3;            // M-slice within the layer group
    const bool isL0 = (w < 4);
    const int n = lane & 15;
    const int q = lane >> 4;
    const int b0 = blockIdx.x * 16;

    // tempo-setter priority: L0 waves permanently favored by the SIMD arbiter
    if (isL0) __builtin_amdgcn_s_setprio(1);

    // h1(-1) = 0 at parity 1 (read as c by L1 at interval 2)
    ((int*)&h1f[1][0])[tid] = 0;

    const int mrow = 16 * wq + n;
    const int m4 = 16 * wq + 4 * q;
    const int rbase = 128 * q + 8 * n;
    const int wbase = (2 * wq + (q >> 1)) * 128 + 8 * n + 4 * (q & 1);

    // ---- weight fragments, single fp16 RTNE (as R10) ----
    half8 wA[2], wB[2];  // L0: A=W_hh0 ; L1: A=W_ih1, B=W_hh1
    auto mkfrag = [&](const float* p, half8& hi) {
#pragma unroll
        for (int j = 0; j < 8; ++j) hi[j] = (_Float16)p[j];
    };
    float4 wih0v = {0, 0, 0, 0}, bv0 = {0, 0, 0, 0}, bv1 = {0, 0, 0, 0}, wfcv = {0, 0, 0, 0};
    if (isL0) {
#pragma unroll
        for (int k = 0; k < 2; ++k) mkfrag(W_hh0 + mrow * 64 + 32 * k + 8 * q, wA[k]);
        wih0v = *(const float4*)(W_ih0 + m4);
        bv0 = *(const float4*)(b_ih0 + m4);
        { float4 t = *(const float4*)(b_hh0 + m4); bv0.x += t.x; bv0.y += t.y; bv0.z += t.z; bv0.w += t.w; }
    } else {
#pragma unroll
        for (int k = 0; k < 2; ++k) {
            mkfrag(W_ih1 + mrow * 64 + 32 * k + 8 * q, wA[k]);
            mkfrag(W_hh1 + mrow * 64 + 32 * k + 8 * q, wB[k]);
        }
        bv1 = *(const float4*)(b_ih1 + m4);
        { float4 t = *(const float4*)(b_hh1 + m4); bv1.x += t.x; bv1.y += t.y; bv1.z += t.z; bv1.w += t.w; }
        wfcv = *(const float4*)(W_fc + m4);
    }

    const float* xp = x + (long)(b0 + n) * TT;

    auto epi_write = [&](const floatx4& A, short* pf) {
        float h[4];
#pragma unroll
        for (int r = 0; r < 4; ++r) h[r] = fast_tanh(A[r]);
        uint2 u;
        u.x = pk16(h[0], h[1]);
        u.y = pk16(h[2], h[3]);
        *(uint2*)&pf[wbase] = u;
    };

    // L0 interval: read h0[rp] (exposed, issued first), single chained
    // accumulator (no epilogue adds), write h0[wp]
    auto stepL0 = [&](int rp, int wp, float xvv) {
        half8 b0v = *(const half8*)&h0f[rp][rbase];
        half8 b1v = *(const half8*)&h0f[rp][rbase + 512];
        floatx4 aA = {__builtin_fmaf(xvv, wih0v.x, bv0.x), __builtin_fmaf(xvv, wih0v.y, bv0.y),
                      __builtin_fmaf(xvv, wih0v.z, bv0.z), __builtin_fmaf(xvv, wih0v.w, bv0.w)};
        aA = __builtin_amdgcn_mfma_f32_16x16x32_f16(wA[0], b0v, aA, 0, 0, 0);
        aA = __builtin_amdgcn_mfma_f32_16x16x32_f16(wA[1], b1v, aA, 0, 0, 0);
        epi_write(aA, &h0f[wp][0]);
    };

    // L1 interval: c-reads issued first; single 4-deep chained accumulator -
    // bp MFMAs (register-ready) issue immediately and hide the c-read; then
    // c0,c1 chain in. No epilogue adds. Late h0 prefetch after epi_write
    // (R8's port-burst win).
    auto stepL1 = [&](int rc, int rbn, int wp, half8* bp) {
        half8 c0 = *(const half8*)&h1f[rc][rbase];
        half8 c1 = *(const half8*)&h1f[rc][rbase + 512];
        floatx4 aA = {bv1.x, bv1.y, bv1.z, bv1.w};
        aA = __builtin_amdgcn_mfma_f32_16x16x32_f16(wA[0], bp[0], aA, 0, 0, 0);
        aA = __builtin_amdgcn_mfma_f32_16x16x32_f16(wA[1], bp[1], aA, 0, 0, 0);
        aA = __builtin_amdgcn_mfma_f32_16x16x32_f16(wB[0], c0, aA, 0, 0, 0);
        aA = __builtin_amdgcn_mfma_f32_16x16x32_f16(wB[1], c1, aA, 0, 0, 0);
        epi_write(aA, &h1f[wp][0]);
        // late prefetch: LDS port idle here; h0f[rbn] stable this interval;
        // completion before next-interval overwrite = validated FIFO property.
        bp[0] = *(const half8*)&h0f[rbn][rbase];
        bp[1] = *(const half8*)&h0f[rbn][rbase + 512];
    };

    // ---- interval 0: L0 writes h0(0) -> parity 0 ----
    float xv = 0.f, xnext = 0.f;
    if (isL0) {
        const float xv0 = xp[0];
        float h[4];
#pragma unroll
        for (int r = 0; r < 4; ++r)
            h[r] = fast_tanh(__builtin_fmaf(xv0, f4e(wih0v, r), f4e(bv0, r)));
        uint2 u; u.x = pk16(h[0], h[1]); u.y = pk16(h[2], h[3]);
        *(uint2*)&h0f[0][wbase] = u;
        xv = xp[1];
        xnext = xp[2];
    }
    BAR();

    // ---- interval 1: L0 h0(1); L1 prefetches h0(0) ----
    half8 bp[2];
    if (isL0) {
        stepL0(0, 1, xv);
        xv = xnext; xnext = xp[3];
    } else {
        bp[0] = *(const half8*)&h0f[0][rbase];
        bp[1] = *(const half8*)&h0f[0][rbase + 512];
    }
    BAR();

    // ---- main loop: intervals i = 2..511 (pairs) ----
    // interval i: L0 computes h0(i); L1 computes h1(i-2), prefetches h0(i-1)
    for (int i = 2; i < 511; i += 2) {
        // P = 0
        if (isL0) {
            stepL0(1, 0, xv);
            xv = xnext; xnext = xp[(i + 2) & (TT - 1)];
        } else {
            stepL1(1, 1, 0, bp);
        }
        BAR();
        // P = 1
        if (isL0) {
            stepL0(0, 1, xv);
            xv = xnext; xnext = xp[(i + 3) & (TT - 1)];
        } else {
            stepL1(0, 0, 1, bp);
        }
        BAR();
    }

    // ---- tail interval 512: L1 computes h1(510), prefetches h0(511) ----
    if (!isL0) stepL1(1, 1, 0, bp);
    BAR();

    // ---- tail interval 513: L1 computes h1(511) in regs + FC dot ----
    float p = 0.f;
    if (!isL0) {
        half8 c0 = *(const half8*)&h1f[0][rbase];        // h1(510), parity 0
        half8 c1 = *(const half8*)&h1f[0][rbase + 512];
        floatx4 aA = {bv1.x, bv1.y, bv1.z, bv1.w};
        aA = __builtin_amdgcn_mfma_f32_16x16x32_f16(wA[0], bp[0], aA, 0, 0, 0);  // h0(511)
        aA = __builtin_amdgcn_mfma_f32_16x16x32_f16(wA[1], bp[1], aA, 0, 0, 0);
        aA = __builtin_amdgcn_mfma_f32_16x16x32_f16(wB[0], c0, aA, 0, 0, 0);
        aA = __builtin_amdgcn_mfma_f32_16x16x32_f16(wB[1], c1, aA, 0, 0, 0);
#pragma unroll
        for (int r = 0; r < 4; ++r) {
            const float h = fast_tanh(aA[r]);
            p = __builtin_fmaf(h, f4e(wfcv, r), p);
        }
        p += __shfl_xor(p, 16, 64);
        p += __shfl_xor(p, 32, 64);
        if (lane < 16) red[wq][lane] = p;
    }
    if (isL0) __builtin_amdgcn_s_setprio(0);
    __syncthreads();
    if (w == 4 && lane < 16)
        out[b0 + lane] = red[0][lane] + red[1][lane] + red[2][lane] + red[3][lane] + b_fc[0];
}

extern "C" void kernel_launch(void* const* d_in, const int* in_sizes, int n_in,
                              void* d_out, int out_size, void* d_ws, size_t ws_size,
                              hipStream_t stream) {
    const float* x     = (const float*)d_in[0];
    const float* W_ih0 = (const float*)d_in[1];
    const float* W_hh0 = (const float*)d_in[2];
    const float* b_ih0 = (const float*)d_in[3];
    const float* b_hh0 = (const float*)d_in[4];
    const float* W_ih1 = (const float*)d_in[5];
    const float* W_hh1 = (const float*)d_in[6];
    const float* b_ih1 = (const float*)d_in[7];
    const float* b_hh1 = (const float*)d_in[8];
    const float* W_fc  = (const float*)d_in[9];
    const float* b_fc  = (const float*)d_in[10];
    float* out = (float*)d_out;

    rnn2_prio2<<<128, 512, 0, stream>>>(x, W_ih0, W_hh0, b_ih0, b_hh0,
                                        W_ih1, W_hh1, b_ih1, b_hh1,
                                        W_fc, b_fc, out);
}

// Round 17
// 203.467 us; speedup vs baseline: 1.0140x; 1.0140x over previous
//
#include <hip/hip_runtime.h>

#define TT 512

typedef _Float16 half8 __attribute__((ext_vector_type(8)));
typedef __attribute__((ext_vector_type(4))) float floatx4;

// raw workgroup barrier (no vmcnt/lgkmcnt drain); LDS FIFO is in-order per CU,
// validated R6-R12 (reads issued pre-barrier stay bit-exact vs post-barrier
// overwrites across 512 steps).
#define BAR() do { __asm__ volatile("" ::: "memory"); \
                   __builtin_amdgcn_s_barrier();      \
                   __asm__ volatile("" ::: "memory"); } while (0)

// 5-op tanh (R10 win, -32%): tanh(z) = fma(-2, rcp(exp2(z*2log2e)+1), 1).
__device__ __forceinline__ float fast_tanh(float z) {
#if __has_builtin(__builtin_amdgcn_exp2f)
    const float e = __builtin_amdgcn_exp2f(z * 2.8853900817779268f);
#else
    const float e = exp2f(z * 2.8853900817779268f);
#endif
#if __has_builtin(__builtin_amdgcn_rcpf)
    const float r = __builtin_amdgcn_rcpf(e + 1.f);
#else
    const float r = __frcp_rn(e + 1.f);
#endif
    return __builtin_fmaf(-2.f, r, 1.f);
}
__device__ __forceinline__ float f4e(const float4& v, int r) {
    return (r == 0) ? v.x : (r == 1) ? v.y : (r == 2) ? v.z : v.w;
}
__device__ __forceinline__ unsigned pk16(float a, float b) {
    const unsigned ua = __builtin_bit_cast(unsigned short, (_Float16)a);
    const unsigned ub = __builtin_bit_cast(unsigned short, (_Float16)b);
    return ua | (ub << 16);
}

// FINAL CHAMPION (R14, 141.4 us counter-level; session 223 -> 141).
// Structure: lag-2 layer pipeline, 128 blocks x 8 waves (2/SIMD), 16 batch
// cols/block. Interval i: waves 0-3 compute h0(i) (own-recurrence ds_read
// exposed, issued first); waves 4-7 compute h1(i-2) on PREFETCHED h0 regs +
// h1(i-3) read at interval start; h0(i-1) prefetch issues AFTER epi_write
// (R8: off the post-barrier LDS port burst). One raw barrier per interval;
// h0/h1 double-buffered by parity.
// Key wins: 5-op tanh (R10, -32%: the __expf/__fdividef form lowered to
// ~15 VALU and sat on the serial tanh chain); full MFMA C-in chaining (R14,
// -5%: deletes the 4 v_adds/step off the tanh-input path - dependent MFMA
// accumulation is cheaper than parallel MFMAs + v_add merge, R11).
// Bounded-out alternatives (R1-R16): concentration, 4-wave merge, flag-sync,
// setprio x3, accumulator splits, x-preload, port-stagger, K=16 identity.
// Remaining T_int ~660 cy = irreducible lag-1 LDS exchange + dep-MFMA +
// tanh tail + 8-wave barrier wake: a dependency-chain floor (512 serial
// steps), not a memory/compute roofline (MfmaUtil 7%, VALUBusy 22%, HBM 0.2%).
__global__ void __launch_bounds__(512, 1)
rnn2_chain(const float* __restrict__ x,
           const float* __restrict__ W_ih0, const float* __restrict__ W_hh0,
           const float* __restrict__ b_ih0, const float* __restrict__ b_hh0,
           const float* __restrict__ W_ih1, const float* __restrict__ W_hh1,
           const float* __restrict__ b_ih1, const float* __restrict__ b_hh1,
           const float* __restrict__ W_fc, const float* __restrict__ b_fc,
           float* __restrict__ out)
{
    __shared__ short h0f[2][1024];  // [parity][chunk*512 + 128q + 8n + j], fp16
    __shared__ short h1f[2][1024];
    __shared__ float red[4][16];

    const int tid = threadIdx.x;
    const int lane = tid & 63;
    const int w = tid >> 6;          // 0..7
    const int wq = w & 3;            // M-slice within the layer group
    const bool isL0 = (w < 4);
    const int n = lane & 15;
    const int q = lane >> 4;
    const int b0 = blockIdx.x * 16;

    // h1(-1) = 0 at parity 1 (read as c by L1 at interval 2)
    ((int*)&h1f[1][0])[tid] = 0;

    const int mrow = 16 * wq + n;
    const int m4 = 16 * wq + 4 * q;
    const int rbase = 128 * q + 8 * n;
    const int wbase = (2 * wq + (q >> 1)) * 128 + 8 * n + 4 * (q & 1);

    // ---- weight fragments, single fp16 RTNE (as R10) ----
    half8 wA[2], wB[2];  // L0: A=W_hh0 ; L1: A=W_ih1, B=W_hh1
    auto mkfrag = [&](const float* p, half8& hi) {
#pragma unroll
        for (int j = 0; j < 8; ++j) hi[j] = (_Float16)p[j];
    };
    float4 wih0v = {0, 0, 0, 0}, bv0 = {0, 0, 0, 0}, bv1 = {0, 0, 0, 0}, wfcv = {0, 0, 0, 0};
    if (isL0) {
#pragma unroll
        for (int k = 0; k < 2; ++k) mkfrag(W_hh0 + mrow * 64 + 32 * k + 8 * q, wA[k]);
        wih0v = *(const float4*)(W_ih0 + m4);
        bv0 = *(const float4*)(b_ih0 + m4);
        { float4 t = *(const float4*)(b_hh0 + m4); bv0.x += t.x; bv0.y += t.y; bv0.z += t.z; bv0.w += t.w; }
    } else {
#pragma unroll
        for (int k = 0; k < 2; ++k) {
            mkfrag(W_ih1 + mrow * 64 + 32 * k + 8 * q, wA[k]);
            mkfrag(W_hh1 + mrow * 64 + 32 * k + 8 * q, wB[k]);
        }
        bv1 = *(const float4*)(b_ih1 + m4);
        { float4 t = *(const float4*)(b_hh1 + m4); bv1.x += t.x; bv1.y += t.y; bv1.z += t.z; bv1.w += t.w; }
        wfcv = *(const float4*)(W_fc + m4);
    }

    const float* xp = x + (long)(b0 + n) * TT;

    auto epi_write = [&](const floatx4& A, short* pf) {
        float h[4];
#pragma unroll
        for (int r = 0; r < 4; ++r) h[r] = fast_tanh(A[r]);
        uint2 u;
        u.x = pk16(h[0], h[1]);
        u.y = pk16(h[2], h[3]);
        *(uint2*)&pf[wbase] = u;
    };

    // L0 interval: read h0[rp] (exposed, issued first), single chained
    // accumulator (no epilogue adds), write h0[wp]
    auto stepL0 = [&](int rp, int wp, float xvv) {
        half8 b0v = *(const half8*)&h0f[rp][rbase];
        half8 b1v = *(const half8*)&h0f[rp][rbase + 512];
        floatx4 aA = {__builtin_fmaf(xvv, wih0v.x, bv0.x), __builtin_fmaf(xvv, wih0v.y, bv0.y),
                      __builtin_fmaf(xvv, wih0v.z, bv0.z), __builtin_fmaf(xvv, wih0v.w, bv0.w)};
        aA = __builtin_amdgcn_mfma_f32_16x16x32_f16(wA[0], b0v, aA, 0, 0, 0);
        aA = __builtin_amdgcn_mfma_f32_16x16x32_f16(wA[1], b1v, aA, 0, 0, 0);
        epi_write(aA, &h0f[wp][0]);
    };

    // L1 interval: c-reads issued first; single 4-deep chained accumulator -
    // bp MFMAs (register-ready) issue immediately and hide the c-read; then
    // c0,c1 chain in. No epilogue adds. Late h0 prefetch after epi_write
    // (R8's port-burst win).
    auto stepL1 = [&](int rc, int rbn, int wp, half8* bp) {
        half8 c0 = *(const half8*)&h1f[rc][rbase];
        half8 c1 = *(const half8*)&h1f[rc][rbase + 512];
        floatx4 aA = {bv1.x, bv1.y, bv1.z, bv1.w};
        aA = __builtin_amdgcn_mfma_f32_16x16x32_f16(wA[0], bp[0], aA, 0, 0, 0);
        aA = __builtin_amdgcn_mfma_f32_16x16x32_f16(wA[1], bp[1], aA, 0, 0, 0);
        aA = __builtin_amdgcn_mfma_f32_16x16x32_f16(wB[0], c0, aA, 0, 0, 0);
        aA = __builtin_amdgcn_mfma_f32_16x16x32_f16(wB[1], c1, aA, 0, 0, 0);
        epi_write(aA, &h1f[wp][0]);
        // late prefetch: LDS port idle here; h0f[rbn] stable this interval;
        // completion before next-interval overwrite = validated FIFO property.
        bp[0] = *(const half8*)&h0f[rbn][rbase];
        bp[1] = *(const half8*)&h0f[rbn][rbase + 512];
    };

    // ---- interval 0: L0 writes h0(0) -> parity 0 ----
    float xv = 0.f, xnext = 0.f;
    if (isL0) {
        const float xv0 = xp[0];
        float h[4];
#pragma unroll
        for (int r = 0; r < 4; ++r)
            h[r] = fast_tanh(__builtin_fmaf(xv0, f4e(wih0v, r), f4e(bv0, r)));
        uint2 u; u.x = pk16(h[0], h[1]); u.y = pk16(h[2], h[3]);
        *(uint2*)&h0f[0][wbase] = u;
        xv = xp[1];
        xnext = xp[2];
    }
    BAR();

    // ---- interval 1: L0 h0(1); L1 prefetches h0(0) ----
    half8 bp[2];
    if (isL0) {
        stepL0(0, 1, xv);
        xv = xnext; xnext = xp[3];
    } else {
        bp[0] = *(const half8*)&h0f[0][rbase];
        bp[1] = *(const half8*)&h0f[0][rbase + 512];
    }
    BAR();

    // ---- main loop: intervals i = 2..511 (pairs) ----
    // interval i: L0 computes h0(i); L1 computes h1(i-2), prefetches h0(i-1)
    for (int i = 2; i < 511; i += 2) {
        // P = 0
        if (isL0) {
            stepL0(1, 0, xv);
            xv = xnext; xnext = xp[(i + 2) & (TT - 1)];
        } else {
            stepL1(1, 1, 0, bp);
        }
        BAR();
        // P = 1
        if (isL0) {
            stepL0(0, 1, xv);
            xv = xnext; xnext = xp[(i + 3) & (TT - 1)];
        } else {
            stepL1(0, 0, 1, bp);
        }
        BAR();
    }

    // ---- tail interval 512: L1 computes h1(510), prefetches h0(511) ----
    if (!isL0) stepL1(1, 1, 0, bp);
    BAR();

    // ---- tail interval 513: L1 computes h1(511) in regs + FC dot ----
    float p = 0.f;
    if (!isL0) {
        half8 c0 = *(const half8*)&h1f[0][rbase];        // h1(510), parity 0
        half8 c1 = *(const half8*)&h1f[0][rbase + 512];
        floatx4 aA = {bv1.x, bv1.y, bv1.z, bv1.w};
        aA = __builtin_amdgcn_mfma_f32_16x16x32_f16(wA[0], bp[0], aA, 0, 0, 0);  // h0(511)
        aA = __builtin_amdgcn_mfma_f32_16x16x32_f16(wA[1], bp[1], aA, 0, 0, 0);
        aA = __builtin_amdgcn_mfma_f32_16x16x32_f16(wB[0], c0, aA, 0, 0, 0);
        aA = __builtin_amdgcn_mfma_f32_16x16x32_f16(wB[1], c1, aA, 0, 0, 0);
#pragma unroll
        for (int r = 0; r < 4; ++r) {
            const float h = fast_tanh(aA[r]);
            p = __builtin_fmaf(h, f4e(wfcv, r), p);
        }
        p += __shfl_xor(p, 16, 64);
        p += __shfl_xor(p, 32, 64);
        if (lane < 16) red[wq][lane] = p;
    }
    __syncthreads();
    if (w == 4 && lane < 16)
        out[b0 + lane] = red[0][lane] + red[1][lane] + red[2][lane] + red[3][lane] + b_fc[0];
}

extern "C" void kernel_launch(void* const* d_in, const int* in_sizes, int n_in,
                              void* d_out, int out_size, void* d_ws, size_t ws_size,
                              hipStream_t stream) {
    const float* x     = (const float*)d_in[0];
    const float* W_ih0 = (const float*)d_in[1];
    const float* W_hh0 = (const float*)d_in[2];
    const float* b_ih0 = (const float*)d_in[3];
    const float* b_hh0 = (const float*)d_in[4];
    const float* W_ih1 = (const float*)d_in[5];
    const float* W_hh1 = (const float*)d_in[6];
    const float* b_ih1 = (const float*)d_in[7];
    const float* b_hh1 = (const float*)d_in[8];
    const float* W_fc  = (const float*)d_in[9];
    const float* b_fc  = (const float*)d_in[10];
    float* out = (float*)d_out;

    rnn2_chain<<<128, 512, 0, stream>>>(x, W_ih0, W_hh0, b_ih0, b_hh0,
                                        W_ih1, W_hh1, b_ih1, b_hh1,
                                        W_fc, b_fc, out);
}